// Round 6
// baseline (166.034 us; speedup 1.0000x reference)
//
#include <hip/hip_runtime.h>

#define IN_DIM 128
#define OUT_DIM 128

typedef __attribute__((ext_vector_type(8))) short short8v;   // 8 bf16 = 4 VGPRs
typedef __attribute__((ext_vector_type(4))) float float4v;
typedef __attribute__((ext_vector_type(4))) unsigned int uint4v;

__device__ __forceinline__ ushort f2bf(float f) {
    unsigned int u = __builtin_bit_cast(unsigned int, f);
    unsigned int r = (u + 0x7fffu + ((u >> 16) & 1u)) >> 16;   // RNE
    return (ushort)r;
}

// pack two f32 -> two bf16 in one dword (HW cvt_pk on gfx950 if available)
__device__ __forceinline__ unsigned int pk2bf(float x, float y) {
#if __has_builtin(__builtin_amdgcn_cvt_pk_bf16_f32)
    typedef __attribute__((ext_vector_type(2))) __bf16 bf2;
    bf2 r = __builtin_amdgcn_cvt_pk_bf16_f32(x, y);
    return __builtin_bit_cast(unsigned int, r);
#else
    return (unsigned int)f2bf(x) | ((unsigned int)f2bf(y) << 16);
#endif
}

__device__ __forceinline__ float bflo(unsigned int v) {
    return __builtin_bit_cast(float, v << 16);
}
__device__ __forceinline__ float bfhi(unsigned int v) {
    return __builtin_bit_cast(float, v & 0xffff0000u);
}

// ---------------- Kernel 0: prep ----------------
// blocks [0, nb_rp): row_ptr[n] = lower_bound(edst, n)     (edst sorted)
// blocks [nb_rp, nb_rp+16): Wt[n][k] = bf16(W[k][n]), row stride 136.
__global__ __launch_bounds__(256) void prep_kernel(const int* __restrict__ edst,
                                                   int* __restrict__ rp,
                                                   const float* __restrict__ W,
                                                   ushort* __restrict__ Wt,
                                                   int E, int N, int nb_rp) {
    int bid = blockIdx.x;
    if (bid < nb_rp) {
        int n = bid * 256 + threadIdx.x;
        if (n <= N) {
            int lo = 0, hi = E;
            while (lo < hi) {
                int mid = (lo + hi) >> 1;
                if (edst[mid] < n) lo = mid + 1; else hi = mid;
            }
            rp[n] = lo;
        }
    } else {
        int k0 = (bid - nb_rp) * 8;
        int n = threadIdx.x & 127;
        int half = threadIdx.x >> 7;
#pragma unroll
        for (int kp = 0; kp < 2; ++kp) {
            int k = k0 + (half * 2 + kp) * 2;
            float v0 = W[k * 128 + n];          // coalesced across lanes
            float v1 = W[(k + 1) * 128 + n];
            *(unsigned int*)&Wt[n * 136 + k] = pk2bf(v0, v1);
        }
    }
}

// ---------------- Kernel 1: T(bf16) = H @ W via MFMA ----------------
// Block 256 thr = 4 waves; 64-row x 128-col tile, K=128 unrolled.
// A-frag = Wt rows (K-contiguous, from LDS); B-frag = H rows (K-contiguous,
// loaded directly global->reg). D[n][m] C-layout: lane holds 4 consecutive n
// of one output row m -> packed 8 B stores.
__global__ __launch_bounds__(256) void gemm_kernel(const float* __restrict__ H,
                                                   const ushort* __restrict__ Wt_g,
                                                   ushort* __restrict__ T, int M) {
    __shared__ ushort Ws[128 * 136];   // 34816 B

    const int t = threadIdx.x;
    const int row0 = blockIdx.x * 64;

#pragma unroll
    for (int f = t; f < 2176; f += 256)
        ((short8v*)Ws)[f] = ((const short8v*)Wt_g)[f];

    const int w = t >> 6;
    const int l = t & 63;
    const int m16 = l & 15;
    const int kq = (l >> 4) * 8;
    const int gr = row0 + w * 16 + m16;

    float4 h[8];
    if (gr < M) {
#pragma unroll
        for (int ks = 0; ks < 4; ++ks) {
            h[ks * 2]     = *(const float4*)&H[gr * 128 + ks * 32 + kq];
            h[ks * 2 + 1] = *(const float4*)&H[gr * 128 + ks * 32 + kq + 4];
        }
    } else {
#pragma unroll
        for (int i = 0; i < 8; ++i) h[i] = make_float4(0.f, 0.f, 0.f, 0.f);
    }

    short8v bfrag[4];
#pragma unroll
    for (int ks = 0; ks < 4; ++ks) {
        uint4v u;
        u[0] = pk2bf(h[ks * 2].x, h[ks * 2].y);
        u[1] = pk2bf(h[ks * 2].z, h[ks * 2].w);
        u[2] = pk2bf(h[ks * 2 + 1].x, h[ks * 2 + 1].y);
        u[3] = pk2bf(h[ks * 2 + 1].z, h[ks * 2 + 1].w);
        bfrag[ks] = __builtin_bit_cast(short8v, u);
    }

    __syncthreads();   // Ws ready

    float4v acc[8];
#pragma unroll
    for (int nt = 0; nt < 8; ++nt) acc[nt] = (float4v){0.f, 0.f, 0.f, 0.f};

#pragma unroll
    for (int ks = 0; ks < 4; ++ks) {
#pragma unroll
        for (int nt = 0; nt < 8; ++nt) {
            short8v afrag = *(const short8v*)&Ws[(nt * 16 + m16) * 136 + ks * 32 + kq];
            acc[nt] = __builtin_amdgcn_mfma_f32_16x16x32_bf16(afrag, bfrag[ks], acc[nt], 0, 0, 0);
        }
    }

    if (gr < M) {
        const int q4 = (l >> 4) * 4;
#pragma unroll
        for (int nt = 0; nt < 8; ++nt) {
            unsigned int p0 = pk2bf(acc[nt][0], acc[nt][1]);
            unsigned int p1 = pk2bf(acc[nt][2], acc[nt][3]);
            uint2 o = make_uint2(p0, p1);
            *(uint2*)&T[gr * 128 + nt * 16 + q4] = o;
        }
    }
}

// ---------------- Kernel 2: out[n][:] = b + sum_{e in seg(n)} w_e * T[src_e][:] ----------------
// One wave per node. Quarter-wave gather: 16 lanes cover one T row (256 B)
// with dwordx4 each; 4 edges per load instruction. COMPILE-TIME-UNROLLED
// chunks (64-edge full / 32-edge short path) so the compiler hoists 16 (resp
// 8) independent gathers before the FMA pass -> deep vmcnt queue. Padding
// lanes carry src=0, w=0: row-0 gathers hit one hot line (no extra FETCH).
__global__ __launch_bounds__(256) void scatter_kernel(const unsigned int* __restrict__ T4,
                                                      const int* __restrict__ esrc,
                                                      const float* __restrict__ ew,
                                                      const int* __restrict__ rp,
                                                      const float* __restrict__ b,
                                                      float* __restrict__ out) {
    const int node = blockIdx.x * 4 + (threadIdx.x >> 6);
    const int lane = threadIdx.x & 63;
    const int q    = lane >> 4;          // quarter 0..3
    const int cl   = lane & 15;          // col group: cols cl*8 .. +8
    const unsigned int coloff = (unsigned int)cl * 4u;   // uint index within row

    const int s = rp[node];
    const int e = rp[node + 1];

    float a0 = 0.f, a1 = 0.f, a2 = 0.f, a3 = 0.f;
    float a4 = 0.f, a5 = 0.f, a6 = 0.f, a7 = 0.f;

    for (int c = s; c < e; c += 64) {
        int idx = c + lane;
        int srcl = 0;
        float wl = 0.f;
        if (idx < e) { srcl = esrc[idx]; wl = ew[idx]; }
        int nn = e - c;

        if (nn > 32) {
            // full 64-edge chunk: 16 gathers in flight
#pragma unroll
            for (int j = 0; j < 64; j += 8) {
                int   s0 = __shfl(srcl, j + q);
                float w0 = __shfl(wl,   j + q);
                int   s1 = __shfl(srcl, j + 4 + q);
                float w1 = __shfl(wl,   j + 4 + q);

                uint4 v0 = *(const uint4*)&T4[(unsigned int)s0 * 64u + coloff];
                uint4 v1 = *(const uint4*)&T4[(unsigned int)s1 * 64u + coloff];

                a0 += w0 * bflo(v0.x); a1 += w0 * bfhi(v0.x);
                a2 += w0 * bflo(v0.y); a3 += w0 * bfhi(v0.y);
                a4 += w0 * bflo(v0.z); a5 += w0 * bfhi(v0.z);
                a6 += w0 * bflo(v0.w); a7 += w0 * bfhi(v0.w);

                a0 += w1 * bflo(v1.x); a1 += w1 * bfhi(v1.x);
                a2 += w1 * bflo(v1.y); a3 += w1 * bfhi(v1.y);
                a4 += w1 * bflo(v1.z); a5 += w1 * bfhi(v1.z);
                a6 += w1 * bflo(v1.w); a7 += w1 * bfhi(v1.w);
            }
        } else {
            // short chunk (<=32 real edges): 8 gathers in flight
#pragma unroll
            for (int j = 0; j < 32; j += 8) {
                int   s0 = __shfl(srcl, j + q);
                float w0 = __shfl(wl,   j + q);
                int   s1 = __shfl(srcl, j + 4 + q);
                float w1 = __shfl(wl,   j + 4 + q);

                uint4 v0 = *(const uint4*)&T4[(unsigned int)s0 * 64u + coloff];
                uint4 v1 = *(const uint4*)&T4[(unsigned int)s1 * 64u + coloff];

                a0 += w0 * bflo(v0.x); a1 += w0 * bfhi(v0.x);
                a2 += w0 * bflo(v0.y); a3 += w0 * bfhi(v0.y);
                a4 += w0 * bflo(v0.z); a5 += w0 * bfhi(v0.z);
                a6 += w0 * bflo(v0.w); a7 += w0 * bfhi(v0.w);

                a0 += w1 * bflo(v1.x); a1 += w1 * bfhi(v1.x);
                a2 += w1 * bflo(v1.y); a3 += w1 * bfhi(v1.y);
                a4 += w1 * bflo(v1.z); a5 += w1 * bfhi(v1.z);
                a6 += w1 * bflo(v1.w); a7 += w1 * bfhi(v1.w);
            }
        }
    }

    // combine the 4 quarters: lanes {l, l^16, l^32, l^48} hold same cols
    a0 += __shfl_xor(a0, 16); a1 += __shfl_xor(a1, 16);
    a2 += __shfl_xor(a2, 16); a3 += __shfl_xor(a3, 16);
    a4 += __shfl_xor(a4, 16); a5 += __shfl_xor(a5, 16);
    a6 += __shfl_xor(a6, 16); a7 += __shfl_xor(a7, 16);
    a0 += __shfl_xor(a0, 32); a1 += __shfl_xor(a1, 32);
    a2 += __shfl_xor(a2, 32); a3 += __shfl_xor(a3, 32);
    a4 += __shfl_xor(a4, 32); a5 += __shfl_xor(a5, 32);
    a6 += __shfl_xor(a6, 32); a7 += __shfl_xor(a7, 32);

    if (q == 0) {
        float4 b0 = *(const float4*)&b[cl * 8];
        float4 b1 = *(const float4*)&b[cl * 8 + 4];
        float4 o0 = make_float4(a0 + b0.x, a1 + b0.y, a2 + b0.z, a3 + b0.w);
        float4 o1 = make_float4(a4 + b1.x, a5 + b1.y, a6 + b1.z, a7 + b1.w);
        *(float4*)&out[node * 128 + cl * 8]     = o0;
        *(float4*)&out[node * 128 + cl * 8 + 4] = o1;
    }
}

extern "C" void kernel_launch(void* const* d_in, const int* in_sizes, int n_in,
                              void* d_out, int out_size, void* d_ws, size_t ws_size,
                              hipStream_t stream) {
    const float* H    = (const float*)d_in[0];
    const int*   esrc = (const int*)d_in[1];
    const int*   edst = (const int*)d_in[2];
    const float* ew   = (const float*)d_in[3];
    const float* W    = (const float*)d_in[4];
    const float* b    = (const float*)d_in[5];
    float* out = (float*)d_out;

    const int M = in_sizes[0] / IN_DIM;   // 50000 nodes
    const int E = in_sizes[1];            // 1,600,000 edges

    // Workspace layout
    ushort* T   = (ushort*)d_ws;                                   // M*128*2 bytes
    size_t  off = (size_t)M * 128 * 2;
    ushort* Wt  = (ushort*)((char*)d_ws + off);                    // 128*136*2 = 34816 B
    off += 128 * 136 * 2;
    int*    rp  = (int*)((char*)d_ws + off);                       // (M+1) ints

    const int nb_rp = (M + 1 + 255) / 256;   // 196
    prep_kernel<<<nb_rp + 16, 256, 0, stream>>>(edst, rp, W, Wt, E, M, nb_rp);

    gemm_kernel<<<(M + 63) / 64, 256, 0, stream>>>(H, Wt, T, M);

    scatter_kernel<<<(M + 3) / 4, 256, 0, stream>>>((const unsigned int*)T, esrc, ew, rp, b, out);
}

// Round 7
// 155.392 us; speedup vs baseline: 1.0685x; 1.0685x over previous
//
#include <hip/hip_runtime.h>

#define IN_DIM 128
#define OUT_DIM 128

typedef __attribute__((ext_vector_type(8))) short short8v;   // 8 bf16 = 4 VGPRs
typedef __attribute__((ext_vector_type(4))) float float4v;
typedef __attribute__((ext_vector_type(4))) unsigned int uint4v;

__device__ __forceinline__ ushort f2bf(float f) {
    unsigned int u = __builtin_bit_cast(unsigned int, f);
    unsigned int r = (u + 0x7fffu + ((u >> 16) & 1u)) >> 16;   // RNE
    return (ushort)r;
}

// pack two f32 -> two bf16 in one dword (HW cvt_pk on gfx950 if available)
__device__ __forceinline__ unsigned int pk2bf(float x, float y) {
#if __has_builtin(__builtin_amdgcn_cvt_pk_bf16_f32)
    typedef __attribute__((ext_vector_type(2))) __bf16 bf2;
    bf2 r = __builtin_amdgcn_cvt_pk_bf16_f32(x, y);
    return __builtin_bit_cast(unsigned int, r);
#else
    return (unsigned int)f2bf(x) | ((unsigned int)f2bf(y) << 16);
#endif
}

__device__ __forceinline__ float bflo(unsigned int v) {
    return __builtin_bit_cast(float, v << 16);
}
__device__ __forceinline__ float bfhi(unsigned int v) {
    return __builtin_bit_cast(float, v & 0xffff0000u);
}

// ---------------- Kernel 0: prep ----------------
// blocks [0, nb_rp): row_ptr[n] = lower_bound(edst, n)     (edst sorted)
// blocks [nb_rp, nb_rp+16): Wt[n][k] = bf16(W[k][n]), row stride 136.
__global__ __launch_bounds__(256) void prep_kernel(const int* __restrict__ edst,
                                                   int* __restrict__ rp,
                                                   const float* __restrict__ W,
                                                   ushort* __restrict__ Wt,
                                                   int E, int N, int nb_rp) {
    int bid = blockIdx.x;
    if (bid < nb_rp) {
        int n = bid * 256 + threadIdx.x;
        if (n <= N) {
            int lo = 0, hi = E;
            while (lo < hi) {
                int mid = (lo + hi) >> 1;
                if (edst[mid] < n) lo = mid + 1; else hi = mid;
            }
            rp[n] = lo;
        }
    } else {
        int k0 = (bid - nb_rp) * 8;
        int n = threadIdx.x & 127;
        int half = threadIdx.x >> 7;
#pragma unroll
        for (int kp = 0; kp < 2; ++kp) {
            int k = k0 + (half * 2 + kp) * 2;
            float v0 = W[k * 128 + n];          // coalesced across lanes
            float v1 = W[(k + 1) * 128 + n];
            *(unsigned int*)&Wt[n * 136 + k] = pk2bf(v0, v1);
        }
    }
}

// ---------------- Kernel 1: T(bf16) = H @ W via MFMA ----------------
// Block 256 thr = 4 waves; 64-row x 128-col tile, K=128 unrolled.
// A-frag = Wt rows (K-contiguous, from LDS); B-frag = H rows (K-contiguous,
// loaded directly global->reg). D[n][m] C-layout: lane holds 4 consecutive n
// of one output row m -> packed 8 B stores.
__global__ __launch_bounds__(256) void gemm_kernel(const float* __restrict__ H,
                                                   const ushort* __restrict__ Wt_g,
                                                   ushort* __restrict__ T, int M) {
    __shared__ ushort Ws[128 * 136];   // 34816 B

    const int t = threadIdx.x;
    const int row0 = blockIdx.x * 64;

#pragma unroll
    for (int f = t; f < 2176; f += 256)
        ((short8v*)Ws)[f] = ((const short8v*)Wt_g)[f];

    const int w = t >> 6;
    const int l = t & 63;
    const int m16 = l & 15;
    const int kq = (l >> 4) * 8;
    const int gr = row0 + w * 16 + m16;

    float4 h[8];
    if (gr < M) {
#pragma unroll
        for (int ks = 0; ks < 4; ++ks) {
            h[ks * 2]     = *(const float4*)&H[gr * 128 + ks * 32 + kq];
            h[ks * 2 + 1] = *(const float4*)&H[gr * 128 + ks * 32 + kq + 4];
        }
    } else {
#pragma unroll
        for (int i = 0; i < 8; ++i) h[i] = make_float4(0.f, 0.f, 0.f, 0.f);
    }

    short8v bfrag[4];
#pragma unroll
    for (int ks = 0; ks < 4; ++ks) {
        uint4v u;
        u[0] = pk2bf(h[ks * 2].x, h[ks * 2].y);
        u[1] = pk2bf(h[ks * 2].z, h[ks * 2].w);
        u[2] = pk2bf(h[ks * 2 + 1].x, h[ks * 2 + 1].y);
        u[3] = pk2bf(h[ks * 2 + 1].z, h[ks * 2 + 1].w);
        bfrag[ks] = __builtin_bit_cast(short8v, u);
    }

    __syncthreads();   // Ws ready

    float4v acc[8];
#pragma unroll
    for (int nt = 0; nt < 8; ++nt) acc[nt] = (float4v){0.f, 0.f, 0.f, 0.f};

#pragma unroll
    for (int ks = 0; ks < 4; ++ks) {
#pragma unroll
        for (int nt = 0; nt < 8; ++nt) {
            short8v afrag = *(const short8v*)&Ws[(nt * 16 + m16) * 136 + ks * 32 + kq];
            acc[nt] = __builtin_amdgcn_mfma_f32_16x16x32_bf16(afrag, bfrag[ks], acc[nt], 0, 0, 0);
        }
    }

    if (gr < M) {
        const int q4 = (l >> 4) * 4;
#pragma unroll
        for (int nt = 0; nt < 8; ++nt) {
            unsigned int p0 = pk2bf(acc[nt][0], acc[nt][1]);
            unsigned int p1 = pk2bf(acc[nt][2], acc[nt][3]);
            uint2 o = make_uint2(p0, p1);
            *(uint2*)&T[gr * 128 + nt * 16 + q4] = o;
        }
    }
}

// ---------------- Kernel 2: out[n][:] = b + sum_{e in seg(n)} w_e * T[src_e][:] ----------------
// PERSISTENT grid-stride: 2048 blocks x 4 waves; each wave loops nodes with
// stride 8192 (removes the 12.5k-block dispatch tail). Per node: R4-proven
// inner loop — lane owns 2 cols; batches of 8 readlane-broadcast metas + 8
// full-wave row gathers in flight; weight-0 pad makes tails branch-free.
__global__ __launch_bounds__(256) void scatter_kernel(const unsigned int* __restrict__ T2,
                                                      const int* __restrict__ esrc,
                                                      const float* __restrict__ ew,
                                                      const int* __restrict__ rp,
                                                      const float* __restrict__ b,
                                                      float* __restrict__ out, int M) {
    const int wave_id = blockIdx.x * 4 + (threadIdx.x >> 6);
    const int nwaves  = gridDim.x * 4;
    const int lane = threadIdx.x & 63;
    const int col = lane << 1;

    const float2 bias = *(const float2*)&b[col];

    for (int node = wave_id; node < M; node += nwaves) {
        const int s = rp[node];
        const int e = rp[node + 1];

        float ax = bias.x, ay = bias.y;

        for (int c = s; c < e; c += 64) {
            int idx = c + lane;
            int srcl = 0;
            float wl = 0.f;
            if (idx < e) { srcl = esrc[idx]; wl = ew[idx]; }
            int wli = __builtin_bit_cast(int, wl);
            int nn = e - c;
            if (nn > 64) nn = 64;

            for (int j = 0; j < nn; j += 8) {
                int ss[8];
                float ww[8];
                unsigned int vv[8];
#pragma unroll
                for (int q = 0; q < 8; ++q) {
                    ss[q] = __builtin_amdgcn_readlane(srcl, j + q);
                    ww[q] = __builtin_bit_cast(float, __builtin_amdgcn_readlane(wli, j + q));
                }
#pragma unroll
                for (int q = 0; q < 8; ++q)
                    vv[q] = T2[(unsigned int)ss[q] * 64u + (unsigned int)lane];
#pragma unroll
                for (int q = 0; q < 8; ++q) {
                    ax += ww[q] * bflo(vv[q]);
                    ay += ww[q] * bfhi(vv[q]);
                }
            }
        }

        *(float2*)&out[node * 128 + col] = make_float2(ax, ay);
    }
}

extern "C" void kernel_launch(void* const* d_in, const int* in_sizes, int n_in,
                              void* d_out, int out_size, void* d_ws, size_t ws_size,
                              hipStream_t stream) {
    const float* H    = (const float*)d_in[0];
    const int*   esrc = (const int*)d_in[1];
    const int*   edst = (const int*)d_in[2];
    const float* ew   = (const float*)d_in[3];
    const float* W    = (const float*)d_in[4];
    const float* b    = (const float*)d_in[5];
    float* out = (float*)d_out;

    const int M = in_sizes[0] / IN_DIM;   // 50000 nodes
    const int E = in_sizes[1];            // 1,600,000 edges

    // Workspace layout
    ushort* T   = (ushort*)d_ws;                                   // M*128*2 bytes
    size_t  off = (size_t)M * 128 * 2;
    ushort* Wt  = (ushort*)((char*)d_ws + off);                    // 128*136*2 = 34816 B
    off += 128 * 136 * 2;
    int*    rp  = (int*)((char*)d_ws + off);                       // (M+1) ints

    const int nb_rp = (M + 1 + 255) / 256;   // 196
    prep_kernel<<<nb_rp + 16, 256, 0, stream>>>(edst, rp, W, Wt, E, M, nb_rp);

    gemm_kernel<<<(M + 63) / 64, 256, 0, stream>>>(H, Wt, T, M);

    scatter_kernel<<<2048, 256, 0, stream>>>((const unsigned int*)T, esrc, ew, rp, b, out, M);
}

// Round 8
// 149.118 us; speedup vs baseline: 1.1134x; 1.0421x over previous
//
#include <hip/hip_runtime.h>

#define IN_DIM 128
#define OUT_DIM 128

typedef __attribute__((ext_vector_type(8))) short short8v;   // 8 bf16 = 4 VGPRs
typedef __attribute__((ext_vector_type(4))) float float4v;
typedef __attribute__((ext_vector_type(4))) unsigned int uint4v;

__device__ __forceinline__ ushort f2bf(float f) {
    unsigned int u = __builtin_bit_cast(unsigned int, f);
    unsigned int r = (u + 0x7fffu + ((u >> 16) & 1u)) >> 16;   // RNE
    return (ushort)r;
}

// pack two f32 -> two bf16 in one dword (HW cvt_pk on gfx950 if available)
__device__ __forceinline__ unsigned int pk2bf(float x, float y) {
#if __has_builtin(__builtin_amdgcn_cvt_pk_bf16_f32)
    typedef __attribute__((ext_vector_type(2))) __bf16 bf2;
    bf2 r = __builtin_amdgcn_cvt_pk_bf16_f32(x, y);
    return __builtin_bit_cast(unsigned int, r);
#else
    return (unsigned int)f2bf(x) | ((unsigned int)f2bf(y) << 16);
#endif
}

__device__ __forceinline__ float bflo(unsigned int v) {
    return __builtin_bit_cast(float, v << 16);
}
__device__ __forceinline__ float bfhi(unsigned int v) {
    return __builtin_bit_cast(float, v & 0xffff0000u);
}

// ---------------- Kernel 0: prep (Wt only, 16 blocks) ----------------
// Wt[n][k] = bf16(W[k][n]), row stride 136. Coalesced fp32 reads, b32 stores.
__global__ __launch_bounds__(256) void prep_kernel(const float* __restrict__ W,
                                                   ushort* __restrict__ Wt) {
    int k0 = blockIdx.x * 8;
    int n = threadIdx.x & 127;
    int half = threadIdx.x >> 7;
#pragma unroll
    for (int kp = 0; kp < 2; ++kp) {
        int k = k0 + (half * 2 + kp) * 2;
        float v0 = W[k * 128 + n];          // coalesced across lanes
        float v1 = W[(k + 1) * 128 + n];
        *(unsigned int*)&Wt[n * 136 + k] = pk2bf(v0, v1);
    }
}

// ---------------- Kernel 1: T(bf16) = H @ W via MFMA,  + rp tail blocks ----------------
// Blocks [0, nb_gemm): 64-row x 128-col tile, K=128 unrolled (R4-proven core).
// Blocks [nb_gemm, nb_gemm+nb_rp): row_ptr[n] = lower_bound(edst, n) — folded
// here so the binary search overlaps gemm instead of serializing before it.
__global__ __launch_bounds__(256) void gemm_kernel(const float* __restrict__ H,
                                                   const ushort* __restrict__ Wt_g,
                                                   ushort* __restrict__ T, int M,
                                                   const int* __restrict__ edst,
                                                   int* __restrict__ rp,
                                                   int E, int nb_gemm) {
    __shared__ ushort Ws[128 * 136];   // 34816 B

    const int t = threadIdx.x;

    if (blockIdx.x >= nb_gemm) {       // rp tail blocks (block-uniform branch)
        int n = (blockIdx.x - nb_gemm) * 256 + t;
        if (n <= M) {
            int lo = 0, hi = E;
            while (lo < hi) {
                int mid = (lo + hi) >> 1;
                if (edst[mid] < n) lo = mid + 1; else hi = mid;
            }
            rp[n] = lo;
        }
        return;
    }

    const int row0 = blockIdx.x * 64;

#pragma unroll
    for (int f = t; f < 2176; f += 256)
        ((short8v*)Ws)[f] = ((const short8v*)Wt_g)[f];

    const int w = t >> 6;
    const int l = t & 63;
    const int m16 = l & 15;
    const int kq = (l >> 4) * 8;
    const int gr = row0 + w * 16 + m16;

    float4 h[8];
    if (gr < M) {
#pragma unroll
        for (int ks = 0; ks < 4; ++ks) {
            h[ks * 2]     = *(const float4*)&H[gr * 128 + ks * 32 + kq];
            h[ks * 2 + 1] = *(const float4*)&H[gr * 128 + ks * 32 + kq + 4];
        }
    } else {
#pragma unroll
        for (int i = 0; i < 8; ++i) h[i] = make_float4(0.f, 0.f, 0.f, 0.f);
    }

    short8v bfrag[4];
#pragma unroll
    for (int ks = 0; ks < 4; ++ks) {
        uint4v u;
        u[0] = pk2bf(h[ks * 2].x, h[ks * 2].y);
        u[1] = pk2bf(h[ks * 2].z, h[ks * 2].w);
        u[2] = pk2bf(h[ks * 2 + 1].x, h[ks * 2 + 1].y);
        u[3] = pk2bf(h[ks * 2 + 1].z, h[ks * 2 + 1].w);
        bfrag[ks] = __builtin_bit_cast(short8v, u);
    }

    __syncthreads();   // Ws ready

    float4v acc[8];
#pragma unroll
    for (int nt = 0; nt < 8; ++nt) acc[nt] = (float4v){0.f, 0.f, 0.f, 0.f};

#pragma unroll
    for (int ks = 0; ks < 4; ++ks) {
#pragma unroll
        for (int nt = 0; nt < 8; ++nt) {
            short8v afrag = *(const short8v*)&Ws[(nt * 16 + m16) * 136 + ks * 32 + kq];
            acc[nt] = __builtin_amdgcn_mfma_f32_16x16x32_bf16(afrag, bfrag[ks], acc[nt], 0, 0, 0);
        }
    }

    if (gr < M) {
        const int q4 = (l >> 4) * 4;
#pragma unroll
        for (int nt = 0; nt < 8; ++nt) {
            unsigned int p0 = pk2bf(acc[nt][0], acc[nt][1]);
            unsigned int p1 = pk2bf(acc[nt][2], acc[nt][3]);
            uint2 o = make_uint2(p0, p1);
            *(uint2*)&T[gr * 128 + nt * 16 + q4] = o;
        }
    }
}

// ---------------- Kernel 2: out[n][:] = b + sum_{e in seg(n)} w_e * T[src_e][:] ----------------
// R4-proven structure (best measured): one wave per node, block of 4 waves;
// lane owns 2 cols; batches of 8 readlane-broadcast metas + 8 full-wave row
// gathers in flight; weight-0 pad; direct float2 store, no atomics.
__global__ __launch_bounds__(256) void scatter_kernel(const unsigned int* __restrict__ T2,
                                                      const int* __restrict__ esrc,
                                                      const float* __restrict__ ew,
                                                      const int* __restrict__ rp,
                                                      const float* __restrict__ b,
                                                      float* __restrict__ out) {
    const int node = blockIdx.x * 4 + (threadIdx.x >> 6);
    const int lane = threadIdx.x & 63;
    const int col = lane << 1;

    const int s = rp[node];
    const int e = rp[node + 1];

    float2 bias = *(const float2*)&b[col];
    float ax = bias.x, ay = bias.y;

    for (int c = s; c < e; c += 64) {
        int idx = c + lane;
        int srcl = 0;
        float wl = 0.f;
        if (idx < e) { srcl = esrc[idx]; wl = ew[idx]; }
        int wli = __builtin_bit_cast(int, wl);
        int nn = e - c;
        if (nn > 64) nn = 64;

        for (int j = 0; j < nn; j += 8) {
            int ss[8];
            float ww[8];
            unsigned int vv[8];
#pragma unroll
            for (int q = 0; q < 8; ++q) {
                ss[q] = __builtin_amdgcn_readlane(srcl, j + q);
                ww[q] = __builtin_bit_cast(float, __builtin_amdgcn_readlane(wli, j + q));
            }
#pragma unroll
            for (int q = 0; q < 8; ++q)
                vv[q] = T2[(unsigned int)ss[q] * 64u + (unsigned int)lane];
#pragma unroll
            for (int q = 0; q < 8; ++q) {
                ax += ww[q] * bflo(vv[q]);
                ay += ww[q] * bfhi(vv[q]);
            }
        }
    }

    *(float2*)&out[node * 128 + col] = make_float2(ax, ay);
}

extern "C" void kernel_launch(void* const* d_in, const int* in_sizes, int n_in,
                              void* d_out, int out_size, void* d_ws, size_t ws_size,
                              hipStream_t stream) {
    const float* H    = (const float*)d_in[0];
    const int*   esrc = (const int*)d_in[1];
    const int*   edst = (const int*)d_in[2];
    const float* ew   = (const float*)d_in[3];
    const float* W    = (const float*)d_in[4];
    const float* b    = (const float*)d_in[5];
    float* out = (float*)d_out;

    const int M = in_sizes[0] / IN_DIM;   // 50000 nodes
    const int E = in_sizes[1];            // 1,600,000 edges

    // Workspace layout
    ushort* T   = (ushort*)d_ws;                                   // M*128*2 bytes
    size_t  off = (size_t)M * 128 * 2;
    ushort* Wt  = (ushort*)((char*)d_ws + off);                    // 128*136*2 = 34816 B
    off += 128 * 136 * 2;
    int*    rp  = (int*)((char*)d_ws + off);                       // (M+1) ints

    // Wt transpose (16 blocks, ~2 us)
    prep_kernel<<<16, 256, 0, stream>>>(W, Wt);

    // gemm + rp binary-search tail blocks in one dispatch
    const int nb_gemm = (M + 63) / 64;         // 782
    const int nb_rp   = (M + 1 + 255) / 256;   // 196
    gemm_kernel<<<nb_gemm + nb_rp, 256, 0, stream>>>(H, Wt, T, M, edst, rp, E, nb_gemm);

    scatter_kernel<<<(M + 3) / 4, 256, 0, stream>>>((const unsigned int*)T, esrc, ew, rp, b, out);
}

// Round 9
// 145.933 us; speedup vs baseline: 1.1377x; 1.0218x over previous
//
#include <hip/hip_runtime.h>

#define IN_DIM 128
#define OUT_DIM 128

typedef __attribute__((ext_vector_type(8))) short short8v;   // 8 bf16 = 4 VGPRs
typedef __attribute__((ext_vector_type(4))) float float4v;
typedef __attribute__((ext_vector_type(4))) unsigned int uint4v;

__device__ __forceinline__ ushort f2bf(float f) {
    unsigned int u = __builtin_bit_cast(unsigned int, f);
    unsigned int r = (u + 0x7fffu + ((u >> 16) & 1u)) >> 16;   // RNE
    return (ushort)r;
}

__device__ __forceinline__ unsigned int pk2bf(float x, float y) {
#if __has_builtin(__builtin_amdgcn_cvt_pk_bf16_f32)
    typedef __attribute__((ext_vector_type(2))) __bf16 bf2;
    bf2 r = __builtin_amdgcn_cvt_pk_bf16_f32(x, y);
    return __builtin_bit_cast(unsigned int, r);
#else
    return (unsigned int)f2bf(x) | ((unsigned int)f2bf(y) << 16);
#endif
}

// ---------------- Kernel 0: prep (Wt only, 16 blocks) ----------------
// Wt[n][k] = bf16(W[k][n]), row stride 136. Coalesced fp32 reads, b32 stores.
__global__ __launch_bounds__(256) void prep_kernel(const float* __restrict__ W,
                                                   ushort* __restrict__ Wt) {
    int k0 = blockIdx.x * 8;
    int n = threadIdx.x & 127;
    int half = threadIdx.x >> 7;
#pragma unroll
    for (int kp = 0; kp < 2; ++kp) {
        int k = k0 + (half * 2 + kp) * 2;
        float v0 = W[k * 128 + n];          // coalesced across lanes
        float v1 = W[(k + 1) * 128 + n];
        *(unsigned int*)&Wt[n * 136 + k] = pk2bf(v0, v1);
    }
}

// ---------------- Kernel 1: T(int8, per-row scale) = H @ W via MFMA, + rp tail ----------------
// Blocks [0, nb_gemm): 64-row x 128-col tile, K=128 unrolled (R4-proven core).
// Epilogue: per-row absmax (shfl_xor 16/32 over quarter-lanes), quantize row
// to int8 with scale S[row] = rowmax/127 -> halves scatter gather bytes.
// Blocks [nb_gemm, ...): row_ptr[n] = lower_bound(edst, n) (overlaps gemm).
__global__ __launch_bounds__(256) void gemm_kernel(const float* __restrict__ H,
                                                   const ushort* __restrict__ Wt_g,
                                                   unsigned char* __restrict__ T8,
                                                   float* __restrict__ S, int M,
                                                   const int* __restrict__ edst,
                                                   int* __restrict__ rp,
                                                   int E, int nb_gemm) {
    __shared__ ushort Ws[128 * 136];   // 34816 B

    const int t = threadIdx.x;

    if (blockIdx.x >= nb_gemm) {       // rp tail blocks (block-uniform branch)
        int n = (blockIdx.x - nb_gemm) * 256 + t;
        if (n <= M) {
            int lo = 0, hi = E;
            while (lo < hi) {
                int mid = (lo + hi) >> 1;
                if (edst[mid] < n) lo = mid + 1; else hi = mid;
            }
            rp[n] = lo;
        }
        return;
    }

    const int row0 = blockIdx.x * 64;

#pragma unroll
    for (int f = t; f < 2176; f += 256)
        ((short8v*)Ws)[f] = ((const short8v*)Wt_g)[f];

    const int w = t >> 6;
    const int l = t & 63;
    const int m16 = l & 15;
    const int kq = (l >> 4) * 8;
    const int gr = row0 + w * 16 + m16;

    float4 h[8];
    if (gr < M) {
#pragma unroll
        for (int ks = 0; ks < 4; ++ks) {
            h[ks * 2]     = *(const float4*)&H[gr * 128 + ks * 32 + kq];
            h[ks * 2 + 1] = *(const float4*)&H[gr * 128 + ks * 32 + kq + 4];
        }
    } else {
#pragma unroll
        for (int i = 0; i < 8; ++i) h[i] = make_float4(0.f, 0.f, 0.f, 0.f);
    }

    short8v bfrag[4];
#pragma unroll
    for (int ks = 0; ks < 4; ++ks) {
        uint4v u;
        u[0] = pk2bf(h[ks * 2].x, h[ks * 2].y);
        u[1] = pk2bf(h[ks * 2].z, h[ks * 2].w);
        u[2] = pk2bf(h[ks * 2 + 1].x, h[ks * 2 + 1].y);
        u[3] = pk2bf(h[ks * 2 + 1].z, h[ks * 2 + 1].w);
        bfrag[ks] = __builtin_bit_cast(short8v, u);
    }

    __syncthreads();   // Ws ready

    float4v acc[8];
#pragma unroll
    for (int nt = 0; nt < 8; ++nt) acc[nt] = (float4v){0.f, 0.f, 0.f, 0.f};

#pragma unroll
    for (int ks = 0; ks < 4; ++ks) {
#pragma unroll
        for (int nt = 0; nt < 8; ++nt) {
            short8v afrag = *(const short8v*)&Ws[(nt * 16 + m16) * 136 + ks * 32 + kq];
            acc[nt] = __builtin_amdgcn_mfma_f32_16x16x32_bf16(afrag, bfrag[ks], acc[nt], 0, 0, 0);
        }
    }

    // Per-row absmax across this lane's 32 cols, then across the 4 quarter-
    // lanes sharing row gr (l, l^16, l^32, l^48).
    float mx = 0.f;
#pragma unroll
    for (int nt = 0; nt < 8; ++nt) {
#pragma unroll
        for (int k = 0; k < 4; ++k) mx = fmaxf(mx, fabsf(acc[nt][k]));
    }
    mx = fmaxf(mx, __shfl_xor(mx, 16));
    mx = fmaxf(mx, __shfl_xor(mx, 32));

    const float inv = 127.0f / fmaxf(mx, 1e-20f);

    if (gr < M) {
        const int qd = l >> 4;
        if (qd == 0) S[gr] = mx * (1.0f / 127.0f);
#pragma unroll
        for (int nt = 0; nt < 8; ++nt) {
            unsigned int p = 0;
#pragma unroll
            for (int k = 0; k < 4; ++k) {
                int qi = (int)__builtin_rintf(acc[nt][k] * inv);
                qi = qi > 127 ? 127 : (qi < -127 ? -127 : qi);
                p |= ((unsigned int)qi & 0xffu) << (k * 8);
            }
            *(unsigned int*)&T8[gr * 128 + nt * 16 + qd * 4] = p;
        }
    }
}

// ---------------- Kernel 2: out[n][:] = b + sum_{e} w_e * S[src] * T8[src][:] ----------------
// R4-proven structure: one wave per node; lane owns 2 cols (one USHORT = 2
// int8 of the row -> 128 B/edge gather, half of bf16). Batches of 8: meta
// broadcast via readlane (uniform -> scalar path), per-edge scale folded into
// the broadcast weight. Weight-0 pad; direct float2 store, no atomics.
__global__ __launch_bounds__(256) void scatter_kernel(const ushort* __restrict__ T16,
                                                      const float* __restrict__ S,
                                                      const int* __restrict__ esrc,
                                                      const float* __restrict__ ew,
                                                      const int* __restrict__ rp,
                                                      const float* __restrict__ b,
                                                      float* __restrict__ out) {
    const int node = blockIdx.x * 4 + (threadIdx.x >> 6);
    const int lane = threadIdx.x & 63;
    const int col = lane << 1;

    const int s = rp[node];
    const int e = rp[node + 1];

    float2 bias = *(const float2*)&b[col];
    float ax = bias.x, ay = bias.y;

    for (int c = s; c < e; c += 64) {
        int idx = c + lane;
        int srcl = 0;
        float wl = 0.f;
        if (idx < e) { srcl = esrc[idx]; wl = ew[idx]; }
        int wli = __builtin_bit_cast(int, wl);
        int nn = e - c;
        if (nn > 64) nn = 64;

        for (int j = 0; j < nn; j += 8) {
            int ss[8];
            float ws[8];
            ushort vv[8];
#pragma unroll
            for (int q = 0; q < 8; ++q) {
                ss[q] = __builtin_amdgcn_readlane(srcl, j + q);
                float wq = __builtin_bit_cast(float, __builtin_amdgcn_readlane(wli, j + q));
                ws[q] = wq * S[ss[q]];          // uniform address -> scalar load
            }
#pragma unroll
            for (int q = 0; q < 8; ++q)
                vv[q] = T16[(unsigned int)ss[q] * 64u + (unsigned int)lane];
#pragma unroll
            for (int q = 0; q < 8; ++q) {
                int lo8 = (int)(signed char)(vv[q] & 0xff);
                int hi8 = (int)(signed char)(vv[q] >> 8);
                ax += ws[q] * (float)lo8;
                ay += ws[q] * (float)hi8;
            }
        }
    }

    *(float2*)&out[node * 128 + col] = make_float2(ax, ay);
}

extern "C" void kernel_launch(void* const* d_in, const int* in_sizes, int n_in,
                              void* d_out, int out_size, void* d_ws, size_t ws_size,
                              hipStream_t stream) {
    const float* H    = (const float*)d_in[0];
    const int*   esrc = (const int*)d_in[1];
    const int*   edst = (const int*)d_in[2];
    const float* ew   = (const float*)d_in[3];
    const float* W    = (const float*)d_in[4];
    const float* b    = (const float*)d_in[5];
    float* out = (float*)d_out;

    const int M = in_sizes[0] / IN_DIM;   // 50000 nodes
    const int E = in_sizes[1];            // 1,600,000 edges

    // Workspace layout
    unsigned char* T8 = (unsigned char*)d_ws;                       // M*128 bytes (int8)
    size_t off = (size_t)M * 128;
    float* S  = (float*)((char*)d_ws + off);                        // M floats
    off += (size_t)M * 4;
    ushort* Wt = (ushort*)((char*)d_ws + off);                      // 128*136*2 B
    off += 128 * 136 * 2;
    int* rp = (int*)((char*)d_ws + off);                            // (M+1) ints

    // Wt transpose (16 blocks)
    prep_kernel<<<16, 256, 0, stream>>>(W, Wt);

    // gemm (int8 quantized output + per-row scale) + rp tail blocks
    const int nb_gemm = (M + 63) / 64;         // 782
    const int nb_rp   = (M + 1 + 255) / 256;   // 196
    gemm_kernel<<<nb_gemm + nb_rp, 256, 0, stream>>>(H, Wt, T8, S, M, edst, rp, E, nb_gemm);

    scatter_kernel<<<(M + 3) / 4, 256, 0, stream>>>((const ushort*)T8, S, esrc, ew, rp, b, out);
}